// Round 1
// 475.003 us; speedup vs baseline: 1.0077x; 1.0077x over previous
//
#include <hip/hip_runtime.h>

// LIF charge->fire->hard-reset scan over T=4 timesteps.
// x_seq: [T, N] fp32 (T outermost), out: [T, N] fp32 spikes in {0,1}.
// v0 = 0; v_charged = v + (x - v)*0.5f; spike = (v_charged >= 1); v = spike ? 0 : v_charged.
//
// Pure streaming: 619.7 MB compulsory traffic, floor ~98 us at 6.35 TB/s.
// v2 changes vs v1 (478.7 us incl. harness fills):
//  - explicit two-phase body: ALL 2*T=8 nontemporal dwordx4 loads issued before
//    any compute/store -> read burst with 8-deep MLP by construction, single
//    read->write turnaround per thread instead of 4.
//  - block-local stream pairing: thread owns groups (b*512+t) and (b*512+256+t),
//    so each block streams one contiguous 8 KiB window per timestep (v1 paired
//    i with i+half, 155 MB apart -> 2x the distinct far-apart DRAM streams).
//  - per-instruction wave footprint unchanged: 64 lanes x 16 B = 1 KiB contiguous.
// All loads/stores nontemporal: data is touched exactly once, skip L2/L3 alloc.

typedef float f4 __attribute__((ext_vector_type(4)));

constexpr int T_STEPS = 4;

__global__ __launch_bounds__(256) void lif_kernel(const f4* __restrict__ x,
                                                  f4* __restrict__ out,
                                                  long long n4) {
    // Block b owns float4-groups [b*512, b*512+512); thread t owns g0=b*512+t, g1=g0+256.
    long long g0 = (long long)blockIdx.x * 512 + threadIdx.x;
    long long g1 = g0 + 256;

    if (g1 >= n4) {
        // Tail path (not taken for this shape: n4 = 4,841,472 = 9456*512 exactly).
        if (g0 >= n4) return;
        f4 v = {0.f, 0.f, 0.f, 0.f};
#pragma unroll
        for (int t = 0; t < T_STEPS; ++t) {
            f4 xv = __builtin_nontemporal_load(x + (long long)t * n4 + g0);
            f4 s;
#pragma unroll
            for (int k = 0; k < 4; ++k) {
                v[k] = v[k] + (xv[k] - v[k]) * 0.5f;
                float sp = (v[k] >= 1.0f) ? 1.0f : 0.0f;
                s[k] = sp;
                v[k] = (sp != 0.0f) ? 0.0f : v[k];
            }
            __builtin_nontemporal_store(s, out + (long long)t * n4 + g0);
        }
        return;
    }

    // ---- Phase 1: pure read burst. 8 dwordx4 loads in flight, no dependent use.
    f4 x0[T_STEPS], x1[T_STEPS];
#pragma unroll
    for (int t = 0; t < T_STEPS; ++t) {
        x0[t] = __builtin_nontemporal_load(x + (long long)t * n4 + g0);
        x1[t] = __builtin_nontemporal_load(x + (long long)t * n4 + g1);
    }

    // ---- Phase 2: sequential LIF scan (v carried in registers), write burst.
    // Fully unrolled -> all x0/x1 indices compile-time constant -> registers,
    // no scratch (rule: runtime-indexed ext_vector arrays spill).
    f4 v0 = {0.f, 0.f, 0.f, 0.f};
    f4 v1 = {0.f, 0.f, 0.f, 0.f};
#pragma unroll
    for (int t = 0; t < T_STEPS; ++t) {
        f4 s0, s1;
#pragma unroll
        for (int k = 0; k < 4; ++k) {
            // exact reference op order: v_charged = v + (x - v) / 2
            v0[k] = v0[k] + (x0[t][k] - v0[k]) * 0.5f;
            float sp0 = (v0[k] >= 1.0f) ? 1.0f : 0.0f;
            s0[k] = sp0;
            v0[k] = (sp0 != 0.0f) ? 0.0f : v0[k];

            v1[k] = v1[k] + (x1[t][k] - v1[k]) * 0.5f;
            float sp1 = (v1[k] >= 1.0f) ? 1.0f : 0.0f;
            s1[k] = sp1;
            v1[k] = (sp1 != 0.0f) ? 0.0f : v1[k];
        }
        __builtin_nontemporal_store(s0, out + (long long)t * n4 + g0);
        __builtin_nontemporal_store(s1, out + (long long)t * n4 + g1);
    }
}

extern "C" void kernel_launch(void* const* d_in, const int* in_sizes, int n_in,
                              void* d_out, int out_size, void* d_ws, size_t ws_size,
                              hipStream_t stream) {
    const float* x = (const float*)d_in[0];
    float* out = (float*)d_out;

    long long total = (long long)in_sizes[0];   // T * N elements (77,463,552)
    long long n4 = total / T_STEPS / 4;         // float4 groups per timestep (4,841,472)

    int block = 256;
    long long groups_per_block = 512;           // 2 groups per thread
    long long grid = (n4 + groups_per_block - 1) / groups_per_block;  // 9456 blocks

    lif_kernel<<<(int)grid, block, 0, stream>>>((const f4*)x, (f4*)out, n4);
}